// Round 1
// baseline (128.552 us; speedup 1.0000x reference)
//
#include <hip/hip_runtime.h>

#define Bn 512
#define Tn 512
#define Ln 48
#define Cn 128
#define Sn 97            // 2*Ln+1
#define BLANKC 127
#define EPSf 1e-7f
#define NEGf (-1e30f)

// logaddexp matching jnp semantics well within tolerance
__device__ __forceinline__ float lae(float x, float y) {
    float m = fmaxf(x, y);
    return m + __logf(1.0f + __expf(-fabsf(x - y)));
}

__global__ void __launch_bounds__(128) ctc_fwd(
        const int* __restrict__ yt,
        const float* __restrict__ yp,
        float* __restrict__ out)
{
    const int b = blockIdx.x;
    const int s = threadIdx.x;   // state index, 0..127 (valid states < Sn)

    // abuf[parity][2 + state]; indices 0,1 are the NEG pads for s-1 / s-2
    __shared__ float abuf[2][130];

    int  cls    = BLANKC;
    bool allow2 = false;
    if (s < Sn && (s & 1)) {
        const int li = s >> 1;
        cls = yt[b * Ln + li];
        if (s >= 3) allow2 = (cls != yt[b * Ln + li - 1]);
    }
    // per-thread gather pointer: y_pred[b, t, cls] ; advance t via [t*Cn]
    const float* gp = yp + (size_t)b * (Tn * Cn) + cls;

    if (s < 2) { abuf[0][s] = NEGf; abuf[1][s] = NEGf; }

    // t = 0 init: alpha0[0]=lp(blank), alpha0[1]=lp(label0), else NEG
    float r = (s < 2) ? __logf(gp[0] + EPSf) : NEGf;
    abuf[0][2 + s] = r;
    __syncthreads();

    // 4-deep prefetch pipeline (statically indexed registers)
    float v1 = gp[(size_t)1 * Cn];
    float v2 = gp[(size_t)2 * Cn];
    float v3 = gp[(size_t)3 * Cn];
    float v4 = gp[(size_t)4 * Cn];

#define CTC_BODY(tt, vv, pft, dopf)                                   \
    {                                                                 \
        float nv_ = 0.0f;                                             \
        if (dopf) nv_ = gp[(size_t)(pft) * Cn];                       \
        const float* ra = abuf[((tt) - 1) & 1];                       \
        float*       wa = abuf[(tt) & 1];                             \
        float a1 = ra[1 + s];                                         \
        float a2 = allow2 ? ra[s] : NEGf;                             \
        float lp = __logf((vv) + EPSf);                               \
        r = lae(lae(r, a1), a2) + lp;                                 \
        wa[2 + s] = r;                                                \
        __syncthreads();                                              \
        if (dopf) (vv) = nv_;                                         \
    }

    // main: t = 1..504, prefetching t+4..t+7 (max 508, in bounds)
    for (int t = 1; t <= 501; t += 4) {
        CTC_BODY(t + 0, v1, t + 4, true)
        CTC_BODY(t + 1, v2, t + 5, true)
        CTC_BODY(t + 2, v3, t + 6, true)
        CTC_BODY(t + 3, v4, t + 7, true)
    }
    // tail: 505..511 (prefetch 509..511 then drain)
    CTC_BODY(505, v1, 509, true)
    CTC_BODY(506, v2, 510, true)
    CTC_BODY(507, v3, 511, true)
    CTC_BODY(508, v4, 0, false)
    CTC_BODY(509, v1, 0, false)
    CTC_BODY(510, v2, 0, false)
    CTC_BODY(511, v3, 0, false)
#undef CTC_BODY

    if (s == 0) {
        const float* fa = abuf[1];   // alpha at t=511 lives in parity 1
        out[b] = -lae(fa[2 + Sn - 1], fa[2 + Sn - 2]);
    }
}

extern "C" void kernel_launch(void* const* d_in, const int* in_sizes, int n_in,
                              void* d_out, int out_size, void* d_ws, size_t ws_size,
                              hipStream_t stream) {
    const int*   yt  = (const int*)d_in[0];
    const float* yp  = (const float*)d_in[1];
    float*       out = (float*)d_out;
    hipLaunchKernelGGL(ctc_fwd, dim3(Bn), dim3(128), 0, stream, yt, yp, out);
}

// Round 3
// 83.327 us; speedup vs baseline: 1.5427x; 1.5427x over previous
//
#include <hip/hip_runtime.h>

#define Bn 512
#define Tn 512
#define Ln 48
#define Cn 128
#define BLANKC 127
#define EPSf 1e-7f
#define NEGf (-1e30f)
#define LN2f 0.6931471805599453f

// logaddexp in log2 domain: returns log2(2^x + 2^y)
__device__ __forceinline__ float lae2(float x, float y) {
    float m = fmaxf(x, y);
    float d = -fabsf(x - y);
    return m + __log2f(1.0f + exp2f(d));
}

__global__ void __launch_bounds__(64) ctc_fwd(
        const int* __restrict__ yt,
        const float* __restrict__ yp,
        float* __restrict__ out)
{
    const int b = blockIdx.x;
    const int l = threadIdx.x;          // lane; owns states s0=2l (blank), s1=2l+1 (label l)

    int  cls1   = BLANKC;
    bool allow2 = false;
    if (l < Ln) {
        cls1 = yt[b * Ln + l];
        if (l >= 1) allow2 = (cls1 != yt[b * Ln + l - 1]);
    }
    const float* gpB = yp + (size_t)b * (Tn * Cn) + BLANKC;  // blank prob stream
    const float* gpL = yp + (size_t)b * (Tn * Cn) + cls1;    // label prob stream

    // t=0 init (log2 domain): alpha0[0]=lp(blank), alpha0[1]=lp(label0), else NEG
    float a0 = (l == 0) ? __log2f(gpB[0] + EPSf) : NEGf;
    float a1 = (l == 0) ? __log2f(gpL[0] + EPSf) : NEGf;

    // 8-deep prefetch (statically indexed registers)
    float vb0 = gpB[(size_t)1 * Cn], vl0 = gpL[(size_t)1 * Cn];
    float vb1 = gpB[(size_t)2 * Cn], vl1 = gpL[(size_t)2 * Cn];
    float vb2 = gpB[(size_t)3 * Cn], vl2 = gpL[(size_t)3 * Cn];
    float vb3 = gpB[(size_t)4 * Cn], vl3 = gpL[(size_t)4 * Cn];
    float vb4 = gpB[(size_t)5 * Cn], vl4 = gpL[(size_t)5 * Cn];
    float vb5 = gpB[(size_t)6 * Cn], vl5 = gpL[(size_t)6 * Cn];
    float vb6 = gpB[(size_t)7 * Cn], vl6 = gpL[(size_t)7 * Cn];
    float vb7 = gpB[(size_t)8 * Cn], vl7 = gpL[(size_t)8 * Cn];

#define STEP(VB, VL, pft, dopf)                                        \
    {                                                                  \
        float nb_ = 0.0f, nl_ = 0.0f;                                  \
        if (dopf) { nb_ = gpB[(size_t)(pft) * Cn];                     \
                    nl_ = gpL[(size_t)(pft) * Cn]; }                   \
        float lp0 = __log2f((VB) + EPSf);                              \
        float lp1 = __log2f((VL) + EPSf);                              \
        float h1  = __shfl_up(a1, 1);                                  \
        h1 = (l == 0) ? NEGf : h1;                                     \
        float u   = lae2(a1, a0);          /* local; overlaps shfl */  \
        float na0 = lae2(a0, h1) + lp0;                                \
        float h1m = allow2 ? h1 : NEGf;                                \
        float na1 = lae2(u, h1m) + lp1;                                \
        a0 = na0; a1 = na1;                                            \
        if (dopf) { (VB) = nb_; (VL) = nl_; }                          \
    }

    // main: t = 1..496 (62 iters x 8); prefetch t+8..t+15 (max 504, in bounds)
    for (int t = 1; t <= 489; t += 8) {
        STEP(vb0, vl0, t +  8, true)
        STEP(vb1, vl1, t +  9, true)
        STEP(vb2, vl2, t + 10, true)
        STEP(vb3, vl3, t + 11, true)
        STEP(vb4, vl4, t + 12, true)
        STEP(vb5, vl5, t + 13, true)
        STEP(vb6, vl6, t + 14, true)
        STEP(vb7, vl7, t + 15, true)
    }
    // tail: t = 497..511 (regs hold 497..504); prefetch 505..511 then drain
    STEP(vb0, vl0, 505, true)
    STEP(vb1, vl1, 506, true)
    STEP(vb2, vl2, 507, true)
    STEP(vb3, vl3, 508, true)
    STEP(vb4, vl4, 509, true)
    STEP(vb5, vl5, 510, true)
    STEP(vb6, vl6, 511, true)
    STEP(vb7, vl7, 0, false)
    STEP(vb0, vl0, 0, false)
    STEP(vb1, vl1, 0, false)
    STEP(vb2, vl2, 0, false)
    STEP(vb3, vl3, 0, false)
    STEP(vb4, vl4, 0, false)
    STEP(vb5, vl5, 0, false)
    STEP(vb6, vl6, 0, false)
#undef STEP

    // ll = lae(alpha[96], alpha[95]); state96 = lane48.a0, state95 = lane47.a1
    float f96 = __shfl(a0, 48);
    float f95 = __shfl(a1, 47);
    if (l == 0) out[b] = -LN2f * lae2(f96, f95);
}

extern "C" void kernel_launch(void* const* d_in, const int* in_sizes, int n_in,
                              void* d_out, int out_size, void* d_ws, size_t ws_size,
                              hipStream_t stream) {
    const int*   yt  = (const int*)d_in[0];
    const float* yp  = (const float*)d_in[1];
    float*       out = (float*)d_out;
    hipLaunchKernelGGL(ctc_fwd, dim3(Bn), dim3(64), 0, stream, yt, yp, out);
}

// Round 4
// 64.818 us; speedup vs baseline: 1.9833x; 1.2856x over previous
//
#include <hip/hip_runtime.h>

#define Bn 512
#define Tn 512
#define Ln 48
#define Cn 128
#define BLANKC 127
#define EPSf 1e-7f
#define NEGf (-1e30f)
#define LN2f 0.6931471805599453f
#define TINYf 1e-38f

// lane i gets lane i-1's value; lane 0 gets `oldv` (wave_shr:1 DPP, 1-VALU cost)
__device__ __forceinline__ float dpp_shr1(float x, float oldv) {
    int r = __builtin_amdgcn_update_dpp(__float_as_int(oldv), __float_as_int(x),
                                        0x138 /*wave_shr:1*/, 0xF, 0xF, false);
    return __int_as_float(r);
}

// 2-way logaddexp in log2 domain (used once at the end)
__device__ __forceinline__ float lae2f(float x, float y) {
    float m = fmaxf(x, y);
    return m + __log2f(1.0f + exp2f(-fabsf(x - y)));
}

__global__ void __launch_bounds__(64) ctc_fwd(
        const int* __restrict__ yt,
        const float* __restrict__ yp,
        float* __restrict__ out)
{
    const int b = blockIdx.x;
    const int l = threadIdx.x;   // lane; owns states s0=2l (blank), s1=2l+1 (label l)

    int  cls1   = BLANKC;
    bool allow2 = false;
    if (l < Ln) {
        cls1 = yt[b * Ln + l];
        if (l >= 1) allow2 = (cls1 != yt[b * Ln + l - 1]);
    }
    const float* gpB = yp + (size_t)b * (Tn * Cn) + BLANKC;  // blank stream (uniform)
    const float* gpL = yp + (size_t)b * (Tn * Cn) + cls1;    // label stream

    // t=0 init (log2 domain)
    float a0 = (l == 0) ? __log2f(gpB[0] + EPSf) : NEGf;
    float a1 = (l == 0) ? __log2f(gpL[0] + EPSf) : NEGf;

    // 16-deep prefetch (statically indexed registers), t = 1..16
    float vb0  = gpB[(size_t) 1 * Cn], vl0  = gpL[(size_t) 1 * Cn];
    float vb1  = gpB[(size_t) 2 * Cn], vl1  = gpL[(size_t) 2 * Cn];
    float vb2  = gpB[(size_t) 3 * Cn], vl2  = gpL[(size_t) 3 * Cn];
    float vb3  = gpB[(size_t) 4 * Cn], vl3  = gpL[(size_t) 4 * Cn];
    float vb4  = gpB[(size_t) 5 * Cn], vl4  = gpL[(size_t) 5 * Cn];
    float vb5  = gpB[(size_t) 6 * Cn], vl5  = gpL[(size_t) 6 * Cn];
    float vb6  = gpB[(size_t) 7 * Cn], vl6  = gpL[(size_t) 7 * Cn];
    float vb7  = gpB[(size_t) 8 * Cn], vl7  = gpL[(size_t) 8 * Cn];
    float vb8  = gpB[(size_t) 9 * Cn], vl8  = gpL[(size_t) 9 * Cn];
    float vb9  = gpB[(size_t)10 * Cn], vl9  = gpL[(size_t)10 * Cn];
    float vb10 = gpB[(size_t)11 * Cn], vl10 = gpL[(size_t)11 * Cn];
    float vb11 = gpB[(size_t)12 * Cn], vl11 = gpL[(size_t)12 * Cn];
    float vb12 = gpB[(size_t)13 * Cn], vl12 = gpL[(size_t)13 * Cn];
    float vb13 = gpB[(size_t)14 * Cn], vl13 = gpL[(size_t)14 * Cn];
    float vb14 = gpB[(size_t)15 * Cn], vl14 = gpL[(size_t)15 * Cn];
    float vb15 = gpB[(size_t)16 * Cn], vl15 = gpL[(size_t)16 * Cn];

#define STEP(VB, VL, pft, dopf)                                         \
    {                                                                   \
        float nb_ = 0.0f, nl_ = 0.0f;                                   \
        if (dopf) { nb_ = gpB[(size_t)(pft) * Cn];                      \
                    nl_ = gpL[(size_t)(pft) * Cn]; }                    \
        float lp0 = __log2f((VB) + EPSf);                               \
        float lp1 = __log2f((VL) + EPSf);                               \
        float h1  = dpp_shr1(a1, NEGf);                                 \
        float M   = fmaxf(fmaxf(a0, a1), h1);                           \
        float Ml0 = M + lp0;                                            \
        float Ml1 = M + lp1;                                            \
        float e0  = exp2f(a0 - M);                                      \
        float e1  = exp2f(a1 - M);                                      \
        float eh  = exp2f(h1 - M);                                      \
        float ehm = allow2 ? eh : 0.0f;                                 \
        float s0  = fmaxf(e0 + eh, TINYf);                              \
        float s1  = fmaxf(e1 + e0 + ehm, TINYf);                        \
        a0 = Ml0 + __log2f(s0);                                         \
        a1 = Ml1 + __log2f(s1);                                         \
        if (dopf) { (VB) = nb_; (VL) = nl_; }                           \
    }

    // main: t = 1..480 (30 iters x 16); prefetch t+16..t+31 (max 496)
    for (int t = 1; t <= 465; t += 16) {
        STEP(vb0,  vl0,  t + 16, true)
        STEP(vb1,  vl1,  t + 17, true)
        STEP(vb2,  vl2,  t + 18, true)
        STEP(vb3,  vl3,  t + 19, true)
        STEP(vb4,  vl4,  t + 20, true)
        STEP(vb5,  vl5,  t + 21, true)
        STEP(vb6,  vl6,  t + 22, true)
        STEP(vb7,  vl7,  t + 23, true)
        STEP(vb8,  vl8,  t + 24, true)
        STEP(vb9,  vl9,  t + 25, true)
        STEP(vb10, vl10, t + 26, true)
        STEP(vb11, vl11, t + 27, true)
        STEP(vb12, vl12, t + 28, true)
        STEP(vb13, vl13, t + 29, true)
        STEP(vb14, vl14, t + 30, true)
        STEP(vb15, vl15, t + 31, true)
    }
    // t = 481..496: consume, prefetch 497..511
    STEP(vb0,  vl0,  497, true)
    STEP(vb1,  vl1,  498, true)
    STEP(vb2,  vl2,  499, true)
    STEP(vb3,  vl3,  500, true)
    STEP(vb4,  vl4,  501, true)
    STEP(vb5,  vl5,  502, true)
    STEP(vb6,  vl6,  503, true)
    STEP(vb7,  vl7,  504, true)
    STEP(vb8,  vl8,  505, true)
    STEP(vb9,  vl9,  506, true)
    STEP(vb10, vl10, 507, true)
    STEP(vb11, vl11, 508, true)
    STEP(vb12, vl12, 509, true)
    STEP(vb13, vl13, 510, true)
    STEP(vb14, vl14, 511, true)
    STEP(vb15, vl15, 0, false)
    // t = 497..511: drain
    STEP(vb0,  vl0,  0, false)
    STEP(vb1,  vl1,  0, false)
    STEP(vb2,  vl2,  0, false)
    STEP(vb3,  vl3,  0, false)
    STEP(vb4,  vl4,  0, false)
    STEP(vb5,  vl5,  0, false)
    STEP(vb6,  vl6,  0, false)
    STEP(vb7,  vl7,  0, false)
    STEP(vb8,  vl8,  0, false)
    STEP(vb9,  vl9,  0, false)
    STEP(vb10, vl10, 0, false)
    STEP(vb11, vl11, 0, false)
    STEP(vb12, vl12, 0, false)
    STEP(vb13, vl13, 0, false)
    STEP(vb14, vl14, 0, false)
#undef STEP

    // ll = lae(alpha[96], alpha[95]); state96 = lane48.a0, state95 = lane47.a1
    float f96 = __shfl(a0, 48);
    float f95 = __shfl(a1, 47);
    if (l == 0) out[b] = -LN2f * lae2f(f96, f95);
}

extern "C" void kernel_launch(void* const* d_in, const int* in_sizes, int n_in,
                              void* d_out, int out_size, void* d_ws, size_t ws_size,
                              hipStream_t stream) {
    const int*   yt  = (const int*)d_in[0];
    const float* yp  = (const float*)d_in[1];
    float*       out = (float*)d_out;
    hipLaunchKernelGGL(ctc_fwd, dim3(Bn), dim3(64), 0, stream, yt, yp, out);
}

// Round 5
// 64.616 us; speedup vs baseline: 1.9895x; 1.0031x over previous
//
#include <hip/hip_runtime.h>

#define Bn 512
#define Tn 512
#define Ln 48
#define Cn 128
#define BLANKC 127
#define EPSf 1e-7f
#define NEGf (-1e30f)
#define LN2f 0.6931471805599453f
#define TINYf 1e-38f

// lane i gets lane i-1's value; lane 0 gets `oldv` (wave_shr:1 DPP, 1-VALU cost)
__device__ __forceinline__ float dpp_shr1(float x, float oldv) {
    int r = __builtin_amdgcn_update_dpp(__float_as_int(oldv), __float_as_int(x),
                                        0x138 /*wave_shr:1*/, 0xF, 0xF, false);
    return __int_as_float(r);
}

// 2-way logaddexp in log2 domain (used once at the end)
__device__ __forceinline__ float lae2f(float x, float y) {
    float m = fmaxf(x, y);
    return m + __log2f(1.0f + exp2f(-fabsf(x - y)));
}

// launch_bounds(64, 1): grid is only 512 waves on 8192 slots — occupancy is
// irrelevant; give the allocator the full 512-VGPR budget so the 32 in-flight
// prefetch loads (+ their address regs) stay live. R3's default budget (64
// VGPRs) forced the compiler to collapse the pipeline -> ~200 cyc stall/step.
__global__ void __launch_bounds__(64, 1) ctc_fwd(
        const int* __restrict__ yt,
        const float* __restrict__ yp,
        float* __restrict__ out)
{
    const int b = blockIdx.x;
    const int l = threadIdx.x;   // lane; owns states s0=2l (blank), s1=2l+1 (label l)

    int  cls1   = BLANKC;
    bool allow2 = false;
    if (l < Ln) {
        cls1 = yt[b * Ln + l];
        if (l >= 1) allow2 = (cls1 != yt[b * Ln + l - 1]);
    }
    const float* gpB = yp + (size_t)b * (Tn * Cn) + BLANKC;  // blank stream (uniform)
    const float* gpL = yp + (size_t)b * (Tn * Cn) + cls1;    // label stream

    // t=0 init (log2 domain)
    float a0 = (l == 0) ? __log2f(gpB[0] + EPSf) : NEGf;
    float a1 = (l == 0) ? __log2f(gpL[0] + EPSf) : NEGf;

    // 16-deep prefetch (statically indexed registers), t = 1..16
    float vb0  = gpB[(size_t) 1 * Cn], vl0  = gpL[(size_t) 1 * Cn];
    float vb1  = gpB[(size_t) 2 * Cn], vl1  = gpL[(size_t) 2 * Cn];
    float vb2  = gpB[(size_t) 3 * Cn], vl2  = gpL[(size_t) 3 * Cn];
    float vb3  = gpB[(size_t) 4 * Cn], vl3  = gpL[(size_t) 4 * Cn];
    float vb4  = gpB[(size_t) 5 * Cn], vl4  = gpL[(size_t) 5 * Cn];
    float vb5  = gpB[(size_t) 6 * Cn], vl5  = gpL[(size_t) 6 * Cn];
    float vb6  = gpB[(size_t) 7 * Cn], vl6  = gpL[(size_t) 7 * Cn];
    float vb7  = gpB[(size_t) 8 * Cn], vl7  = gpL[(size_t) 8 * Cn];
    float vb8  = gpB[(size_t) 9 * Cn], vl8  = gpL[(size_t) 9 * Cn];
    float vb9  = gpB[(size_t)10 * Cn], vl9  = gpL[(size_t)10 * Cn];
    float vb10 = gpB[(size_t)11 * Cn], vl10 = gpL[(size_t)11 * Cn];
    float vb11 = gpB[(size_t)12 * Cn], vl11 = gpL[(size_t)12 * Cn];
    float vb12 = gpB[(size_t)13 * Cn], vl12 = gpL[(size_t)13 * Cn];
    float vb13 = gpB[(size_t)14 * Cn], vl13 = gpL[(size_t)14 * Cn];
    float vb14 = gpB[(size_t)15 * Cn], vl14 = gpL[(size_t)15 * Cn];
    float vb15 = gpB[(size_t)16 * Cn], vl15 = gpL[(size_t)16 * Cn];

#define STEP(VB, VL, pft, dopf)                                         \
    {                                                                   \
        float nb_ = 0.0f, nl_ = 0.0f;                                   \
        if (dopf) { nb_ = gpB[(size_t)(pft) * Cn];                      \
                    nl_ = gpL[(size_t)(pft) * Cn]; }                    \
        float lp0 = __log2f((VB) + EPSf);                               \
        float lp1 = __log2f((VL) + EPSf);                               \
        float h1  = dpp_shr1(a1, NEGf);                                 \
        float M   = fmaxf(fmaxf(a0, a1), h1);                           \
        float Ml0 = M + lp0;                                            \
        float Ml1 = M + lp1;                                            \
        float e0  = exp2f(a0 - M);                                      \
        float e1  = exp2f(a1 - M);                                      \
        float eh  = exp2f(h1 - M);                                      \
        float ehm = allow2 ? eh : 0.0f;                                 \
        float s0  = fmaxf(e0 + eh, TINYf);                              \
        float s1  = fmaxf(e1 + e0 + ehm, TINYf);                        \
        a0 = Ml0 + __log2f(s0);                                         \
        a1 = Ml1 + __log2f(s1);                                         \
        if (dopf) { (VB) = nb_; (VL) = nl_; }                           \
    }

    // main: t = 1..480 (30 iters x 16); prefetch t+16..t+31 (max 496)
    for (int t = 1; t <= 465; t += 16) {
        STEP(vb0,  vl0,  t + 16, true)
        STEP(vb1,  vl1,  t + 17, true)
        STEP(vb2,  vl2,  t + 18, true)
        STEP(vb3,  vl3,  t + 19, true)
        STEP(vb4,  vl4,  t + 20, true)
        STEP(vb5,  vl5,  t + 21, true)
        STEP(vb6,  vl6,  t + 22, true)
        STEP(vb7,  vl7,  t + 23, true)
        STEP(vb8,  vl8,  t + 24, true)
        STEP(vb9,  vl9,  t + 25, true)
        STEP(vb10, vl10, t + 26, true)
        STEP(vb11, vl11, t + 27, true)
        STEP(vb12, vl12, t + 28, true)
        STEP(vb13, vl13, t + 29, true)
        STEP(vb14, vl14, t + 30, true)
        STEP(vb15, vl15, t + 31, true)
    }
    // t = 481..496: consume, prefetch 497..511
    STEP(vb0,  vl0,  497, true)
    STEP(vb1,  vl1,  498, true)
    STEP(vb2,  vl2,  499, true)
    STEP(vb3,  vl3,  500, true)
    STEP(vb4,  vl4,  501, true)
    STEP(vb5,  vl5,  502, true)
    STEP(vb6,  vl6,  503, true)
    STEP(vb7,  vl7,  504, true)
    STEP(vb8,  vl8,  505, true)
    STEP(vb9,  vl9,  506, true)
    STEP(vb10, vl10, 507, true)
    STEP(vb11, vl11, 508, true)
    STEP(vb12, vl12, 509, true)
    STEP(vb13, vl13, 510, true)
    STEP(vb14, vl14, 511, true)
    STEP(vb15, vl15, 0, false)
    // t = 497..511: drain
    STEP(vb0,  vl0,  0, false)
    STEP(vb1,  vl1,  0, false)
    STEP(vb2,  vl2,  0, false)
    STEP(vb3,  vl3,  0, false)
    STEP(vb4,  vl4,  0, false)
    STEP(vb5,  vl5,  0, false)
    STEP(vb6,  vl6,  0, false)
    STEP(vb7,  vl7,  0, false)
    STEP(vb8,  vl8,  0, false)
    STEP(vb9,  vl9,  0, false)
    STEP(vb10, vl10, 0, false)
    STEP(vb11, vl11, 0, false)
    STEP(vb12, vl12, 0, false)
    STEP(vb13, vl13, 0, false)
    STEP(vb14, vl14, 0, false)
#undef STEP

    // ll = lae(alpha[96], alpha[95]); state96 = lane48.a0, state95 = lane47.a1
    float f96 = __shfl(a0, 48);
    float f95 = __shfl(a1, 47);
    if (l == 0) out[b] = -LN2f * lae2f(f96, f95);
}

extern "C" void kernel_launch(void* const* d_in, const int* in_sizes, int n_in,
                              void* d_out, int out_size, void* d_ws, size_t ws_size,
                              hipStream_t stream) {
    const int*   yt  = (const int*)d_in[0];
    const float* yp  = (const float*)d_in[1];
    float*       out = (float*)d_out;
    hipLaunchKernelGGL(ctc_fwd, dim3(Bn), dim3(64), 0, stream, yt, yp, out);
}

// Round 8
// 41.924 us; speedup vs baseline: 3.0663x; 1.5413x over previous
//
#include <hip/hip_runtime.h>

#define Bn 512
#define Tn 512
#define Ln 48
#define Cn 128
#define BLANKC 127
#define EPSf 1e-7f
#define LN2f 0.6931471805599453f

// value shift: lane i <- lane i-1, lane 0 <- 0  (wave_shr:1, bound_ctrl=1)
template<int CTRL>
__device__ __forceinline__ float dpp_f0(float x) {
    int r = __builtin_amdgcn_update_dpp(0, __float_as_int(x), CTRL, 0xF, 0xF, true);
    return __int_as_float(r);
}
// exponent shift: lane i <- lane i-1, lane 0 keeps its OWN value (old=self, bc=0)
__device__ __forceinline__ int dpp_shr1_keep(int x) {
    return __builtin_amdgcn_update_dpp(x, x, 0x138, 0xF, 0xF, false);
}

__global__ void __launch_bounds__(64, 1) ctc_fwd(
        const int* __restrict__ yt,
        const float* __restrict__ yp,
        float* __restrict__ out)
{
    const int b = blockIdx.x;
    const int l = threadIdx.x;   // lane; owns states s0=2l (blank), s1=2l+1 (label l)

    const bool lab_ok = (l < Ln);
    int  cls1   = BLANKC;
    bool allow2 = false;
    if (lab_ok) {
        cls1 = yt[b * Ln + l];
        if (l >= 1) allow2 = (cls1 != yt[b * Ln + l - 1]);
    }
    const float* gpB = yp + (size_t)b * (Tn * Cn) + BLANKC;
    const float* gpL = yp + (size_t)b * (Tn * Cn) + cls1;

    // ---- per-lane block floating point: true_alpha = a * 2^E ----
    float a0 = (l == 0) ? gpB[0] + EPSf : 0.0f;
    float a1 = (l == 0) ? gpL[0] + EPSf : 0.0f;
    int   E  = 0;

    // 32-deep prefetch, t = 1..32
    float vb0  = gpB[(size_t) 1*Cn], vl0  = gpL[(size_t) 1*Cn];
    float vb1  = gpB[(size_t) 2*Cn], vl1  = gpL[(size_t) 2*Cn];
    float vb2  = gpB[(size_t) 3*Cn], vl2  = gpL[(size_t) 3*Cn];
    float vb3  = gpB[(size_t) 4*Cn], vl3  = gpL[(size_t) 4*Cn];
    float vb4  = gpB[(size_t) 5*Cn], vl4  = gpL[(size_t) 5*Cn];
    float vb5  = gpB[(size_t) 6*Cn], vl5  = gpL[(size_t) 6*Cn];
    float vb6  = gpB[(size_t) 7*Cn], vl6  = gpL[(size_t) 7*Cn];
    float vb7  = gpB[(size_t) 8*Cn], vl7  = gpL[(size_t) 8*Cn];
    float vb8  = gpB[(size_t) 9*Cn], vl8  = gpL[(size_t) 9*Cn];
    float vb9  = gpB[(size_t)10*Cn], vl9  = gpL[(size_t)10*Cn];
    float vb10 = gpB[(size_t)11*Cn], vl10 = gpL[(size_t)11*Cn];
    float vb11 = gpB[(size_t)12*Cn], vl11 = gpL[(size_t)12*Cn];
    float vb12 = gpB[(size_t)13*Cn], vl12 = gpL[(size_t)13*Cn];
    float vb13 = gpB[(size_t)14*Cn], vl13 = gpL[(size_t)14*Cn];
    float vb14 = gpB[(size_t)15*Cn], vl14 = gpL[(size_t)15*Cn];
    float vb15 = gpB[(size_t)16*Cn], vl15 = gpL[(size_t)16*Cn];
    float vb16 = gpB[(size_t)17*Cn], vl16 = gpL[(size_t)17*Cn];
    float vb17 = gpB[(size_t)18*Cn], vl17 = gpL[(size_t)18*Cn];
    float vb18 = gpB[(size_t)19*Cn], vl18 = gpL[(size_t)19*Cn];
    float vb19 = gpB[(size_t)20*Cn], vl19 = gpL[(size_t)20*Cn];
    float vb20 = gpB[(size_t)21*Cn], vl20 = gpL[(size_t)21*Cn];
    float vb21 = gpB[(size_t)22*Cn], vl21 = gpL[(size_t)22*Cn];
    float vb22 = gpB[(size_t)23*Cn], vl22 = gpL[(size_t)23*Cn];
    float vb23 = gpB[(size_t)24*Cn], vl23 = gpL[(size_t)24*Cn];
    float vb24 = gpB[(size_t)25*Cn], vl24 = gpL[(size_t)25*Cn];
    float vb25 = gpB[(size_t)26*Cn], vl25 = gpL[(size_t)26*Cn];
    float vb26 = gpB[(size_t)27*Cn], vl26 = gpL[(size_t)27*Cn];
    float vb27 = gpB[(size_t)28*Cn], vl27 = gpL[(size_t)28*Cn];
    float vb28 = gpB[(size_t)29*Cn], vl28 = gpL[(size_t)29*Cn];
    float vb29 = gpB[(size_t)30*Cn], vl29 = gpL[(size_t)30*Cn];
    float vb30 = gpB[(size_t)31*Cn], vl30 = gpL[(size_t)31*Cn];
    float vb31 = gpB[(size_t)32*Cn], vl31 = gpL[(size_t)32*Cn];

    // one DP step with local scale alignment to the left neighbor
#define STEP(VB, VL, pft, dopf)                                      \
    {                                                                \
        float nb_ = 0.0f, nl_ = 0.0f;                                \
        if (dopf) { nb_ = gpB[(size_t)(pft) * Cn];                   \
                    nl_ = gpL[(size_t)(pft) * Cn]; }                 \
        float p0 = (VB) + EPSf;                                      \
        float p1 = lab_ok ? (VL) + EPSf : 0.0f;                      \
        float h1 = dpp_f0<0x138>(a1);                                \
        int   Eh = dpp_shr1_keep(E);                                 \
        int   dm = max(E, Eh);                                       \
        int   k0 = min(dm - E, 127);                                 \
        int   kh = min(dm - Eh, 127);                                \
        float s0 = __int_as_float((127 - k0) << 23);  /* 2^-k0 */    \
        float sh = __int_as_float((127 - kh) << 23);  /* 2^-kh */    \
        float a0c = a0 * s0, a1c = a1 * s0, h1c = h1 * sh;           \
        E = dm;                                                      \
        float t0 = a0c + h1c;                                        \
        float u  = a1c + (allow2 ? t0 : a0c);                        \
        a0 = t0 * p0;                                                \
        a1 = u * p1;                                                 \
        if (dopf) { (VB) = nb_; (VL) = nl_; }                        \
    }

    // per-lane renorm (no cross-lane): keep stored a ~[0.5,1), fold into E
#define RENORM()                                                     \
    {                                                                \
        float m_ = fmaxf(a0, a1);                                    \
        int   e_ = ((__float_as_int(m_) >> 23) & 0xFF) - 126;        \
        float sc_ = __int_as_float((127 - e_) << 23);                \
        a0 *= sc_; a1 *= sc_;                                        \
        E += e_;                                                     \
    }

    // main: t = 1..448 (14 iters x 32); prefetch t+32 (max 480); renorm /4
    for (int t = 1; t <= 417; t += 32) {
        STEP(vb0,  vl0,  t + 32, true) STEP(vb1,  vl1,  t + 33, true)
        STEP(vb2,  vl2,  t + 34, true) STEP(vb3,  vl3,  t + 35, true)
        RENORM()
        STEP(vb4,  vl4,  t + 36, true) STEP(vb5,  vl5,  t + 37, true)
        STEP(vb6,  vl6,  t + 38, true) STEP(vb7,  vl7,  t + 39, true)
        RENORM()
        STEP(vb8,  vl8,  t + 40, true) STEP(vb9,  vl9,  t + 41, true)
        STEP(vb10, vl10, t + 42, true) STEP(vb11, vl11, t + 43, true)
        RENORM()
        STEP(vb12, vl12, t + 44, true) STEP(vb13, vl13, t + 45, true)
        STEP(vb14, vl14, t + 46, true) STEP(vb15, vl15, t + 47, true)
        RENORM()
        STEP(vb16, vl16, t + 48, true) STEP(vb17, vl17, t + 49, true)
        STEP(vb18, vl18, t + 50, true) STEP(vb19, vl19, t + 51, true)
        RENORM()
        STEP(vb20, vl20, t + 52, true) STEP(vb21, vl21, t + 53, true)
        STEP(vb22, vl22, t + 54, true) STEP(vb23, vl23, t + 55, true)
        RENORM()
        STEP(vb24, vl24, t + 56, true) STEP(vb25, vl25, t + 57, true)
        STEP(vb26, vl26, t + 58, true) STEP(vb27, vl27, t + 59, true)
        RENORM()
        STEP(vb28, vl28, t + 60, true) STEP(vb29, vl29, t + 61, true)
        STEP(vb30, vl30, t + 62, true) STEP(vb31, vl31, t + 63, true)
        RENORM()
    }

    // tail A: t = 449..480 ; prefetch 481..511
    STEP(vb0,  vl0,  481, true) STEP(vb1,  vl1,  482, true)
    STEP(vb2,  vl2,  483, true) STEP(vb3,  vl3,  484, true)
    RENORM()
    STEP(vb4,  vl4,  485, true) STEP(vb5,  vl5,  486, true)
    STEP(vb6,  vl6,  487, true) STEP(vb7,  vl7,  488, true)
    RENORM()
    STEP(vb8,  vl8,  489, true) STEP(vb9,  vl9,  490, true)
    STEP(vb10, vl10, 491, true) STEP(vb11, vl11, 492, true)
    RENORM()
    STEP(vb12, vl12, 493, true) STEP(vb13, vl13, 494, true)
    STEP(vb14, vl14, 495, true) STEP(vb15, vl15, 496, true)
    RENORM()
    STEP(vb16, vl16, 497, true) STEP(vb17, vl17, 498, true)
    STEP(vb18, vl18, 499, true) STEP(vb19, vl19, 500, true)
    RENORM()
    STEP(vb20, vl20, 501, true) STEP(vb21, vl21, 502, true)
    STEP(vb22, vl22, 503, true) STEP(vb23, vl23, 504, true)
    RENORM()
    STEP(vb24, vl24, 505, true) STEP(vb25, vl25, 506, true)
    STEP(vb26, vl26, 507, true) STEP(vb27, vl27, 508, true)
    RENORM()
    STEP(vb28, vl28, 509, true) STEP(vb29, vl29, 510, true)
    STEP(vb30, vl30, 511, true) STEP(vb31, vl31, 0, false)
    RENORM()

    // tail B: t = 481..511 (31 steps), drain
    STEP(vb0,  vl0,  0, false) STEP(vb1,  vl1,  0, false)
    STEP(vb2,  vl2,  0, false) STEP(vb3,  vl3,  0, false)
    RENORM()
    STEP(vb4,  vl4,  0, false) STEP(vb5,  vl5,  0, false)
    STEP(vb6,  vl6,  0, false) STEP(vb7,  vl7,  0, false)
    RENORM()
    STEP(vb8,  vl8,  0, false) STEP(vb9,  vl9,  0, false)
    STEP(vb10, vl10, 0, false) STEP(vb11, vl11, 0, false)
    RENORM()
    STEP(vb12, vl12, 0, false) STEP(vb13, vl13, 0, false)
    STEP(vb14, vl14, 0, false) STEP(vb15, vl15, 0, false)
    RENORM()
    STEP(vb16, vl16, 0, false) STEP(vb17, vl17, 0, false)
    STEP(vb18, vl18, 0, false) STEP(vb19, vl19, 0, false)
    RENORM()
    STEP(vb20, vl20, 0, false) STEP(vb21, vl21, 0, false)
    STEP(vb22, vl22, 0, false) STEP(vb23, vl23, 0, false)
    RENORM()
    STEP(vb24, vl24, 0, false) STEP(vb25, vl25, 0, false)
    STEP(vb26, vl26, 0, false) STEP(vb27, vl27, 0, false)
    RENORM()
    STEP(vb28, vl28, 0, false) STEP(vb29, vl29, 0, false)
    STEP(vb30, vl30, 0, false)
#undef STEP
#undef RENORM

    // ll = log(a96*2^E96 + a95*2^E95); state96 = lane48.a0, state95 = lane47.a1
    float f96 = __shfl(a0, 48);  int E96 = __shfl(E, 48);
    float f95 = __shfl(a1, 47);  int E95 = __shfl(E, 47);
    if (l == 0) {
        int   dm = max(E96, E95);
        int   k6 = min(dm - E96, 127), k5 = min(dm - E95, 127);
        float s6 = __int_as_float((127 - k6) << 23);
        float s5 = __int_as_float((127 - k5) << 23);
        float sum = f96 * s6 + f95 * s5;
        out[b] = -LN2f * (__log2f(sum) + (float)dm);
    }
}

extern "C" void kernel_launch(void* const* d_in, const int* in_sizes, int n_in,
                              void* d_out, int out_size, void* d_ws, size_t ws_size,
                              hipStream_t stream) {
    const int*   yt  = (const int*)d_in[0];
    const float* yp  = (const float*)d_in[1];
    float*       out = (float*)d_out;
    hipLaunchKernelGGL(ctc_fwd, dim3(Bn), dim3(64), 0, stream, yt, yp, out);
}

// Round 9
// 38.858 us; speedup vs baseline: 3.3083x; 1.0789x over previous
//
#include <hip/hip_runtime.h>
#include <stdint.h>

#define Bn 512
#define Tn 512
#define Ln 48
#define Cn 128
#define BLANKC 127
#define EPSf 1e-7f
#define LN2f 0.6931471805599453f

// value shift: lane i <- lane i-1, lane 0 <- 0  (wave_shr:1, bound_ctrl=1)
template<int CTRL>
__device__ __forceinline__ float dpp_f0(float x) {
    int r = __builtin_amdgcn_update_dpp(0, __float_as_int(x), CTRL, 0xF, 0xF, true);
    return __int_as_float(r);
}
// exponent shift: lane i <- lane i-1, lane 0 keeps its OWN value (old=self, bc=0)
__device__ __forceinline__ int dpp_shr1_keep(int x) {
    return __builtin_amdgcn_update_dpp(x, x, 0x138, 0xF, 0xF, false);
}

__global__ void __launch_bounds__(64, 1) ctc_fwd(
        const int* __restrict__ yt,
        const float* __restrict__ yp,
        float* __restrict__ out)
{
    const int b = blockIdx.x;
    const int l = threadIdx.x;   // lane; owns states s0=2l (blank), s1=2l+1 (label l)

    // LDS ring: 4 buffers x 16 rows x 64 lanes (16 KB)
    __shared__ float lds_f[4 * 16 * 64];

    const bool lab_ok = (l < Ln);
    int  cls1   = BLANKC;                   // lanes >=48 stage the blank column
    bool allow2 = false;
    if (lab_ok) {
        cls1 = yt[b * Ln + l];
        if (l >= 1) allow2 = (cls1 != yt[b * Ln + l - 1]);
    }
    const float* gsrc0 = yp + (size_t)b * (Tn * Cn) + cls1;  // per-lane column base

    // ---- t = 0 init (per-lane BFP: true_alpha = a * 2^E) ----
    float t0B = yp[(size_t)b * (Tn * Cn) + BLANKC];
    float t0L = gsrc0[0];
    float a0 = (l == 0) ? t0B + EPSf : 0.0f;
    float a1 = (l == 0) ? t0L + EPSf : 0.0f;
    int   E  = 0;

#define GLDS(GP, LIDX)                                                       \
    __builtin_amdgcn_global_load_lds(                                        \
        (const __attribute__((address_space(1))) uint32_t*)(GP),             \
        (__attribute__((address_space(3))) uint32_t*)&lds_f[LIDX], 4, 0, 0);

    // ---- DMA: stage chunks 0,1,2 (rows t = 0..47) ----
#pragma unroll
    for (int r = 0; r < 16; ++r) GLDS(gsrc0 + r * Cn,          (r << 6))
#pragma unroll
    for (int r = 0; r < 16; ++r) GLDS(gsrc0 + (16 + r) * Cn, (1 << 10) + (r << 6))
#pragma unroll
    for (int r = 0; r < 16; ++r) GLDS(gsrc0 + (32 + r) * Cn, (2 << 10) + (r << 6))
    asm volatile("s_waitcnt vmcnt(16)" ::: "memory");   // chunks 0,1 resident

    // ---- prime ds pipeline: slot (t&3) holds row t; rows 1..4 ----
    float pb1 = lds_f[(1 << 6) + 63], pl1 = lds_f[(1 << 6) + l];
    float pb2 = lds_f[(2 << 6) + 63], pl2 = lds_f[(2 << 6) + l];
    float pb3 = lds_f[(3 << 6) + 63], pl3 = lds_f[(3 << 6) + l];
    float pb0 = lds_f[(4 << 6) + 63], pl0 = lds_f[(4 << 6) + l];

#define DSTEP(PB, PL, ROWB, dopf)                                    \
    {                                                                \
        float nb_ = 0.0f, nl_ = 0.0f;                                \
        if (dopf) { nb_ = lds_f[(ROWB) + 63];                        \
                    nl_ = lds_f[(ROWB) + l]; }                       \
        float p0 = (PB) + EPSf;                                      \
        float p1 = lab_ok ? (PL) + EPSf : 0.0f;                      \
        float h1 = dpp_f0<0x138>(a1);                                \
        int   Eh = dpp_shr1_keep(E);                                 \
        int   dm = max(E, Eh);                                       \
        int   k0 = min(dm - E, 127);                                 \
        int   kh = min(dm - Eh, 127);                                \
        float s0 = __int_as_float((127 - k0) << 23);                 \
        float sh = __int_as_float((127 - kh) << 23);                 \
        float a0c = a0 * s0, a1c = a1 * s0, h1c = h1 * sh;           \
        E = dm;                                                      \
        float t0 = a0c + h1c;                                        \
        float u  = a1c + (allow2 ? t0 : a0c);                        \
        a0 = t0 * p0;                                                \
        a1 = u * p1;                                                 \
        if (dopf) { (PB) = nb_; (PL) = nl_; }                        \
    }

#define RENORM()                                                     \
    {                                                                \
        float m_ = fmaxf(a0, a1);                                    \
        int   e_ = ((__float_as_int(m_) >> 23) & 0xFF) - 126;        \
        float sc_ = __int_as_float((127 - e_) << 23);                \
        a0 *= sc_; a1 *= sc_;                                        \
        E += e_;                                                     \
    }

#define BOUNDARY(CC)                                                 \
    {                                                                \
        int c3_ = (CC) + 3;                                          \
        if (c3_ <= 31) {                                             \
            const float* gc3_ = gsrc0 + (size_t)(c3_ * 16) * Cn;     \
            int ibd_ = (c3_ & 3) << 10;                              \
            _Pragma("unroll")                                        \
            for (int r = 0; r < 16; ++r)                             \
                GLDS(gc3_ + r * Cn, ibd_ + (r << 6))                 \
        }                                                            \
        asm volatile("s_waitcnt vmcnt(16)" ::: "memory");            \
    }

    // ---- chunk 0: steps t = 1..15 (slot = t&3) ----
    DSTEP(pb1, pl1, (5 << 6), true)        // t=1  -> pf row 5
    DSTEP(pb2, pl2, (6 << 6), true)        // t=2
    DSTEP(pb3, pl3, (7 << 6), true)        // t=3
    RENORM()
    DSTEP(pb0, pl0, (8 << 6), true)        // t=4
    DSTEP(pb1, pl1, (9 << 6), true)        // t=5
    DSTEP(pb2, pl2, (10 << 6), true)       // t=6
    DSTEP(pb3, pl3, (11 << 6), true)       // t=7
    RENORM()
    DSTEP(pb0, pl0, (12 << 6), true)       // t=8
    DSTEP(pb1, pl1, (13 << 6), true)       // t=9
    DSTEP(pb2, pl2, (14 << 6), true)       // t=10
    DSTEP(pb3, pl3, (15 << 6), true)       // t=11
    RENORM()
    DSTEP(pb0, pl0, (1 << 10) + (0 << 6), true)  // t=12 -> pf row 16 (chunk1 r0)
    DSTEP(pb1, pl1, (1 << 10) + (1 << 6), true)  // t=13 -> r17
    DSTEP(pb2, pl2, (1 << 10) + (2 << 6), true)  // t=14 -> r18
    DSTEP(pb3, pl3, (1 << 10) + (3 << 6), true)  // t=15 -> r19
    RENORM()
    BOUNDARY(0)

    // ---- chunks 1..30: 16 steps each; chunk c step r: t=16c+r, slot r&3 ----
    for (int c = 1; c <= 30; ++c) {
        const int ib  = (c & 3) << 10;
        const int inx = ((c + 1) & 3) << 10;
        DSTEP(pb0, pl0, ib + (4 << 6), true)   // r=0  -> pf r4
        DSTEP(pb1, pl1, ib + (5 << 6), true)
        DSTEP(pb2, pl2, ib + (6 << 6), true)
        DSTEP(pb3, pl3, ib + (7 << 6), true)
        RENORM()
        DSTEP(pb0, pl0, ib + (8 << 6), true)
        DSTEP(pb1, pl1, ib + (9 << 6), true)
        DSTEP(pb2, pl2, ib + (10 << 6), true)
        DSTEP(pb3, pl3, ib + (11 << 6), true)
        RENORM()
        DSTEP(pb0, pl0, ib + (12 << 6), true)
        DSTEP(pb1, pl1, ib + (13 << 6), true)
        DSTEP(pb2, pl2, ib + (14 << 6), true)
        DSTEP(pb3, pl3, ib + (15 << 6), true)
        RENORM()
        DSTEP(pb0, pl0, inx + (0 << 6), true)  // r=12 -> pf next r0
        DSTEP(pb1, pl1, inx + (1 << 6), true)
        DSTEP(pb2, pl2, inx + (2 << 6), true)
        DSTEP(pb3, pl3, inx + (3 << 6), true)
        RENORM()
        BOUNDARY(c)
    }

    // ---- chunk 31: t = 496..511, no prefetch past end ----
    {
        const int ib = (31 & 3) << 10;
        DSTEP(pb0, pl0, ib + (4 << 6), true)
        DSTEP(pb1, pl1, ib + (5 << 6), true)
        DSTEP(pb2, pl2, ib + (6 << 6), true)
        DSTEP(pb3, pl3, ib + (7 << 6), true)
        RENORM()
        DSTEP(pb0, pl0, ib + (8 << 6), true)
        DSTEP(pb1, pl1, ib + (9 << 6), true)
        DSTEP(pb2, pl2, ib + (10 << 6), true)
        DSTEP(pb3, pl3, ib + (11 << 6), true)
        RENORM()
        DSTEP(pb0, pl0, ib + (12 << 6), true)
        DSTEP(pb1, pl1, ib + (13 << 6), true)
        DSTEP(pb2, pl2, ib + (14 << 6), true)
        DSTEP(pb3, pl3, ib + (15 << 6), true)
        RENORM()
        DSTEP(pb0, pl0, 0, false)
        DSTEP(pb1, pl1, 0, false)
        DSTEP(pb2, pl2, 0, false)
        DSTEP(pb3, pl3, 0, false)
        RENORM()
    }
#undef DSTEP
#undef RENORM
#undef BOUNDARY
#undef GLDS

    // ll = log(a96*2^E96 + a95*2^E95); state96 = lane48.a0, state95 = lane47.a1
    float f96 = __shfl(a0, 48);  int E96 = __shfl(E, 48);
    float f95 = __shfl(a1, 47);  int E95 = __shfl(E, 47);
    if (l == 0) {
        int   dm = max(E96, E95);
        int   k6 = min(dm - E96, 127), k5 = min(dm - E95, 127);
        float s6 = __int_as_float((127 - k6) << 23);
        float s5 = __int_as_float((127 - k5) << 23);
        float sum = f96 * s6 + f95 * s5;
        out[b] = -LN2f * (__log2f(sum) + (float)dm);
    }
}

extern "C" void kernel_launch(void* const* d_in, const int* in_sizes, int n_in,
                              void* d_out, int out_size, void* d_ws, size_t ws_size,
                              hipStream_t stream) {
    const int*   yt  = (const int*)d_in[0];
    const float* yp  = (const float*)d_in[1];
    float*       out = (float*)d_out;
    hipLaunchKernelGGL(ctc_fwd, dim3(Bn), dim3(64), 0, stream, yt, yp, out);
}

// Round 10
// 29.632 us; speedup vs baseline: 4.3383x; 1.3114x over previous
//
#include <hip/hip_runtime.h>

#define Bn 512
#define Tn 512
#define Ln 48
#define Cn 128
#define BLANKC 127
#define EPSf 1e-7f
#define LN2f 0.6931471805599453f

// DPP with 0-fill for out-of-range source lanes (bound_ctrl=1)
template<int CTRL>
__device__ __forceinline__ float dpp_f0(float x) {
    int r = __builtin_amdgcn_update_dpp(0, __float_as_int(x), CTRL, 0xF, 0xF, true);
    return __int_as_float(r);
}
// DPP keep-self for out-of-range lanes (old=self, bound_ctrl=0) — identity for max
template<int CTRL>
__device__ __forceinline__ int dpp_i_keep(int x) {
    return __builtin_amdgcn_update_dpp(x, x, CTRL, 0xF, 0xF, false);
}

// ctrl: 0x138 wave_shr:1 (lane i <- i-1) ; 0x130 wave_shl:1 (lane i <- i+1)
//       0x111/0x112/0x114/0x118 row_shr:1/2/4/8 (within 16-lane row)

__global__ void __launch_bounds__(128, 1) ctc_fwd(
        const int* __restrict__ yt,
        const float* __restrict__ yp,
        float* __restrict__ out)
{
    const int b = blockIdx.x;
    const int w = threadIdx.x >> 6;   // 0 = forward wave, 1 = backward wave
    const int l = threadIdx.x & 63;   // lane; owns states s0=2l, s1=2l+1

    __shared__ float xb0[64], xb1[64];
    __shared__ int   xEb[64];
    __shared__ int   rmax[4];
    __shared__ float rsum[4];

    const bool lab_ok = (l < Ln);
    int  cls1   = BLANKC;
    bool allow2 = false;
    if (lab_ok) {
        cls1 = yt[b * Ln + l];
        if (l >= 1) allow2 = (cls1 != yt[b * Ln + l - 1]);
    }
    const float* gpB = yp + (size_t)b * (Tn * Cn) + BLANKC;
    const float* gpL = yp + (size_t)b * (Tn * Cn) + cls1;

    // per-lane BFP state: true value = v * 2^E
    float a0, a1;     // fwd alphas (wave 0) ; bwd betas (wave 1)
    int   E = 0;

#define RENORM(X0, X1)                                               \
    {                                                                \
        float m_ = fmaxf(X0, X1);                                    \
        int   e_ = ((__float_as_int(m_) >> 23) & 0xFF) - 126;        \
        float sc_ = __int_as_float((127 - e_) << 23);                \
        X0 *= sc_; X1 *= sc_;                                        \
        E += e_;                                                     \
    }

    if (w == 0) {
        // ================= FORWARD: alpha_0 -> alpha_255 (255 steps) ======
        a0 = (l == 0) ? gpB[0] + EPSf : 0.0f;
        a1 = (l == 0) ? gpL[0] + EPSf : 0.0f;

        // 32-deep prefetch: slot k <- row 1+k
        float vb0  = gpB[(size_t) 1*Cn], vl0  = gpL[(size_t) 1*Cn];
        float vb1  = gpB[(size_t) 2*Cn], vl1  = gpL[(size_t) 2*Cn];
        float vb2  = gpB[(size_t) 3*Cn], vl2  = gpL[(size_t) 3*Cn];
        float vb3  = gpB[(size_t) 4*Cn], vl3  = gpL[(size_t) 4*Cn];
        float vb4  = gpB[(size_t) 5*Cn], vl4  = gpL[(size_t) 5*Cn];
        float vb5  = gpB[(size_t) 6*Cn], vl5  = gpL[(size_t) 6*Cn];
        float vb6  = gpB[(size_t) 7*Cn], vl6  = gpL[(size_t) 7*Cn];
        float vb7  = gpB[(size_t) 8*Cn], vl7  = gpL[(size_t) 8*Cn];
        float vb8  = gpB[(size_t) 9*Cn], vl8  = gpL[(size_t) 9*Cn];
        float vb9  = gpB[(size_t)10*Cn], vl9  = gpL[(size_t)10*Cn];
        float vb10 = gpB[(size_t)11*Cn], vl10 = gpL[(size_t)11*Cn];
        float vb11 = gpB[(size_t)12*Cn], vl11 = gpL[(size_t)12*Cn];
        float vb12 = gpB[(size_t)13*Cn], vl12 = gpL[(size_t)13*Cn];
        float vb13 = gpB[(size_t)14*Cn], vl13 = gpL[(size_t)14*Cn];
        float vb14 = gpB[(size_t)15*Cn], vl14 = gpL[(size_t)15*Cn];
        float vb15 = gpB[(size_t)16*Cn], vl15 = gpL[(size_t)16*Cn];
        float vb16 = gpB[(size_t)17*Cn], vl16 = gpL[(size_t)17*Cn];
        float vb17 = gpB[(size_t)18*Cn], vl17 = gpL[(size_t)18*Cn];
        float vb18 = gpB[(size_t)19*Cn], vl18 = gpL[(size_t)19*Cn];
        float vb19 = gpB[(size_t)20*Cn], vl19 = gpL[(size_t)20*Cn];
        float vb20 = gpB[(size_t)21*Cn], vl20 = gpL[(size_t)21*Cn];
        float vb21 = gpB[(size_t)22*Cn], vl21 = gpL[(size_t)22*Cn];
        float vb22 = gpB[(size_t)23*Cn], vl22 = gpL[(size_t)23*Cn];
        float vb23 = gpB[(size_t)24*Cn], vl23 = gpL[(size_t)24*Cn];
        float vb24 = gpB[(size_t)25*Cn], vl24 = gpL[(size_t)25*Cn];
        float vb25 = gpB[(size_t)26*Cn], vl25 = gpL[(size_t)26*Cn];
        float vb26 = gpB[(size_t)27*Cn], vl26 = gpL[(size_t)27*Cn];
        float vb27 = gpB[(size_t)28*Cn], vl27 = gpL[(size_t)28*Cn];
        float vb28 = gpB[(size_t)29*Cn], vl28 = gpL[(size_t)29*Cn];
        float vb29 = gpB[(size_t)30*Cn], vl29 = gpL[(size_t)30*Cn];
        float vb30 = gpB[(size_t)31*Cn], vl30 = gpL[(size_t)31*Cn];
        float vb31 = gpB[(size_t)32*Cn], vl31 = gpL[(size_t)32*Cn];

#define FSTEP(VB, VL, pft, dopf)                                     \
    {                                                                \
        float nb_ = 0.0f, nl_ = 0.0f;                                \
        if (dopf) { nb_ = gpB[(size_t)(pft) * Cn];                   \
                    nl_ = gpL[(size_t)(pft) * Cn]; }                 \
        float p0 = (VB) + EPSf;                                      \
        float p1 = lab_ok ? (VL) + EPSf : 0.0f;                      \
        float h1 = dpp_f0<0x138>(a1);                                \
        int   Eh = dpp_i_keep<0x138>(E);                             \
        int   d_ = Eh - E;                                           \
        int   shA = min(-d_, 0);                                     \
        int   shH = min(d_, 0);                                      \
        E = max(E, Eh);                                              \
        float a0c = ldexpf(a0, shA);                                 \
        float a1c = ldexpf(a1, shA);                                 \
        float h1c = ldexpf(h1, shH);                                 \
        float t0 = a0c + h1c;                                        \
        float u  = a1c + (allow2 ? t0 : a0c);                        \
        a0 = t0 * p0;                                                \
        a1 = u * p1;                                                 \
        if (dopf) { (VB) = nb_; (VL) = nl_; }                        \
    }

#define FBLOCK(TB, dopf)                                                          \
        FSTEP(vb0,  vl0,  (TB)+32, dopf) FSTEP(vb1,  vl1,  (TB)+33, dopf)         \
        FSTEP(vb2,  vl2,  (TB)+34, dopf) FSTEP(vb3,  vl3,  (TB)+35, dopf)         \
        RENORM(a0, a1)                                                            \
        FSTEP(vb4,  vl4,  (TB)+36, dopf) FSTEP(vb5,  vl5,  (TB)+37, dopf)         \
        FSTEP(vb6,  vl6,  (TB)+38, dopf) FSTEP(vb7,  vl7,  (TB)+39, dopf)         \
        RENORM(a0, a1)                                                            \
        FSTEP(vb8,  vl8,  (TB)+40, dopf) FSTEP(vb9,  vl9,  (TB)+41, dopf)         \
        FSTEP(vb10, vl10, (TB)+42, dopf) FSTEP(vb11, vl11, (TB)+43, dopf)         \
        RENORM(a0, a1)                                                            \
        FSTEP(vb12, vl12, (TB)+44, dopf) FSTEP(vb13, vl13, (TB)+45, dopf)         \
        FSTEP(vb14, vl14, (TB)+46, dopf) FSTEP(vb15, vl15, (TB)+47, dopf)         \
        RENORM(a0, a1)                                                            \
        FSTEP(vb16, vl16, (TB)+48, dopf) FSTEP(vb17, vl17, (TB)+49, dopf)         \
        FSTEP(vb18, vl18, (TB)+50, dopf) FSTEP(vb19, vl19, (TB)+51, dopf)         \
        RENORM(a0, a1)                                                            \
        FSTEP(vb20, vl20, (TB)+52, dopf) FSTEP(vb21, vl21, (TB)+53, dopf)         \
        FSTEP(vb22, vl22, (TB)+54, dopf) FSTEP(vb23, vl23, (TB)+55, dopf)         \
        RENORM(a0, a1)                                                            \
        FSTEP(vb24, vl24, (TB)+56, dopf) FSTEP(vb25, vl25, (TB)+57, dopf)         \
        FSTEP(vb26, vl26, (TB)+58, dopf) FSTEP(vb27, vl27, (TB)+59, dopf)         \
        RENORM(a0, a1)                                                            \
        FSTEP(vb28, vl28, (TB)+60, dopf) FSTEP(vb29, vl29, (TB)+61, dopf)         \
        FSTEP(vb30, vl30, (TB)+62, dopf) FSTEP(vb31, vl31, (TB)+63, dopf)         \
        RENORM(a0, a1)

        // main: t = 1..224 (7 x 32), prefetch up to row 256 (valid)
        for (int t = 1; t <= 193; t += 32) { FBLOCK(t, true) }

        // tail: t = 225..255 (31 steps, slots 0..30), no prefetch
        FSTEP(vb0,  vl0,  0, false) FSTEP(vb1,  vl1,  0, false)
        FSTEP(vb2,  vl2,  0, false) FSTEP(vb3,  vl3,  0, false)
        RENORM(a0, a1)
        FSTEP(vb4,  vl4,  0, false) FSTEP(vb5,  vl5,  0, false)
        FSTEP(vb6,  vl6,  0, false) FSTEP(vb7,  vl7,  0, false)
        RENORM(a0, a1)
        FSTEP(vb8,  vl8,  0, false) FSTEP(vb9,  vl9,  0, false)
        FSTEP(vb10, vl10, 0, false) FSTEP(vb11, vl11, 0, false)
        RENORM(a0, a1)
        FSTEP(vb12, vl12, 0, false) FSTEP(vb13, vl13, 0, false)
        FSTEP(vb14, vl14, 0, false) FSTEP(vb15, vl15, 0, false)
        RENORM(a0, a1)
        FSTEP(vb16, vl16, 0, false) FSTEP(vb17, vl17, 0, false)
        FSTEP(vb18, vl18, 0, false) FSTEP(vb19, vl19, 0, false)
        RENORM(a0, a1)
        FSTEP(vb20, vl20, 0, false) FSTEP(vb21, vl21, 0, false)
        FSTEP(vb22, vl22, 0, false) FSTEP(vb23, vl23, 0, false)
        RENORM(a0, a1)
        FSTEP(vb24, vl24, 0, false) FSTEP(vb25, vl25, 0, false)
        FSTEP(vb26, vl26, 0, false) FSTEP(vb27, vl27, 0, false)
        RENORM(a0, a1)
        FSTEP(vb28, vl28, 0, false) FSTEP(vb29, vl29, 0, false)
        FSTEP(vb30, vl30, 0, false)
        RENORM(a0, a1)
#undef FSTEP
#undef FBLOCK
    } else {
        // ================= BACKWARD: beta_511 -> beta_255 (256 steps) =====
        a0 = (l == 48) ? 1.0f : 0.0f;   // beta[2l]   (blank state)
        a1 = (l == 47) ? 1.0f : 0.0f;   // beta[2l+1] (label state)

        // 32-deep prefetch: slot k <- row 511-k
        float vb0  = gpB[(size_t)511*Cn], vl0  = gpL[(size_t)511*Cn];
        float vb1  = gpB[(size_t)510*Cn], vl1  = gpL[(size_t)510*Cn];
        float vb2  = gpB[(size_t)509*Cn], vl2  = gpL[(size_t)509*Cn];
        float vb3  = gpB[(size_t)508*Cn], vl3  = gpL[(size_t)508*Cn];
        float vb4  = gpB[(size_t)507*Cn], vl4  = gpL[(size_t)507*Cn];
        float vb5  = gpB[(size_t)506*Cn], vl5  = gpL[(size_t)506*Cn];
        float vb6  = gpB[(size_t)505*Cn], vl6  = gpL[(size_t)505*Cn];
        float vb7  = gpB[(size_t)504*Cn], vl7  = gpL[(size_t)504*Cn];
        float vb8  = gpB[(size_t)503*Cn], vl8  = gpL[(size_t)503*Cn];
        float vb9  = gpB[(size_t)502*Cn], vl9  = gpL[(size_t)502*Cn];
        float vb10 = gpB[(size_t)501*Cn], vl10 = gpL[(size_t)501*Cn];
        float vb11 = gpB[(size_t)500*Cn], vl11 = gpL[(size_t)500*Cn];
        float vb12 = gpB[(size_t)499*Cn], vl12 = gpL[(size_t)499*Cn];
        float vb13 = gpB[(size_t)498*Cn], vl13 = gpL[(size_t)498*Cn];
        float vb14 = gpB[(size_t)497*Cn], vl14 = gpL[(size_t)497*Cn];
        float vb15 = gpB[(size_t)496*Cn], vl15 = gpL[(size_t)496*Cn];
        float vb16 = gpB[(size_t)495*Cn], vl16 = gpL[(size_t)495*Cn];
        float vb17 = gpB[(size_t)494*Cn], vl17 = gpL[(size_t)494*Cn];
        float vb18 = gpB[(size_t)493*Cn], vl18 = gpL[(size_t)493*Cn];
        float vb19 = gpB[(size_t)492*Cn], vl19 = gpL[(size_t)492*Cn];
        float vb20 = gpB[(size_t)491*Cn], vl20 = gpL[(size_t)491*Cn];
        float vb21 = gpB[(size_t)490*Cn], vl21 = gpL[(size_t)490*Cn];
        float vb22 = gpB[(size_t)489*Cn], vl22 = gpL[(size_t)489*Cn];
        float vb23 = gpB[(size_t)488*Cn], vl23 = gpL[(size_t)488*Cn];
        float vb24 = gpB[(size_t)487*Cn], vl24 = gpL[(size_t)487*Cn];
        float vb25 = gpB[(size_t)486*Cn], vl25 = gpL[(size_t)486*Cn];
        float vb26 = gpB[(size_t)485*Cn], vl26 = gpL[(size_t)485*Cn];
        float vb27 = gpB[(size_t)484*Cn], vl27 = gpL[(size_t)484*Cn];
        float vb28 = gpB[(size_t)483*Cn], vl28 = gpL[(size_t)483*Cn];
        float vb29 = gpB[(size_t)482*Cn], vl29 = gpL[(size_t)482*Cn];
        float vb30 = gpB[(size_t)481*Cn], vl30 = gpL[(size_t)481*Cn];
        float vb31 = gpB[(size_t)480*Cn], vl31 = gpL[(size_t)480*Cn];

        // beta step: g0=b0*p0, g1=b1*p1; nb0=g0+g1; nb1=g1+(g0+allow2*g1)[lane+1]
#define BSTEP(VB, VL, pft, dopf)                                     \
    {                                                                \
        float nb_ = 0.0f, nl_ = 0.0f;                                \
        if (dopf) { nb_ = gpB[(size_t)(pft) * Cn];                   \
                    nl_ = gpL[(size_t)(pft) * Cn]; }                 \
        float p0 = (VB) + EPSf;                                      \
        float p1 = lab_ok ? (VL) + EPSf : 0.0f;                      \
        float g0 = a0 * p0;                                          \
        float g1 = a1 * p1;                                          \
        float w_ = allow2 ? g1 : 0.0f;                               \
        float g0u = dpp_f0<0x130>(g0);                               \
        float wu  = dpp_f0<0x130>(w_);                               \
        int   Eh = dpp_i_keep<0x130>(E);                             \
        int   d_ = Eh - E;                                           \
        int   shA = min(-d_, 0);                                     \
        int   shH = min(d_, 0);                                      \
        E = max(E, Eh);                                              \
        float up = g0u + wu;                                         \
        a0 = ldexpf(g0 + g1, shA);                                   \
        a1 = ldexpf(g1, shA) + ldexpf(up, shH);                      \
        if (dopf) { (VB) = nb_; (VL) = nl_; }                        \
    }

#define BBLOCK(RB, dopf)                                                          \
        BSTEP(vb0,  vl0,  (RB)-32, dopf) BSTEP(vb1,  vl1,  (RB)-33, dopf)         \
        BSTEP(vb2,  vl2,  (RB)-34, dopf) BSTEP(vb3,  vl3,  (RB)-35, dopf)         \
        RENORM(a0, a1)                                                            \
        BSTEP(vb4,  vl4,  (RB)-36, dopf) BSTEP(vb5,  vl5,  (RB)-37, dopf)         \
        BSTEP(vb6,  vl6,  (RB)-38, dopf) BSTEP(vb7,  vl7,  (RB)-39, dopf)         \
        RENORM(a0, a1)                                                            \
        BSTEP(vb8,  vl8,  (RB)-40, dopf) BSTEP(vb9,  vl9,  (RB)-41, dopf)         \
        BSTEP(vb10, vl10, (RB)-42, dopf) BSTEP(vb11, vl11, (RB)-43, dopf)         \
        RENORM(a0, a1)                                                            \
        BSTEP(vb12, vl12, (RB)-44, dopf) BSTEP(vb13, vl13, (RB)-45, dopf)         \
        BSTEP(vb14, vl14, (RB)-46, dopf) BSTEP(vb15, vl15, (RB)-47, dopf)         \
        RENORM(a0, a1)                                                            \
        BSTEP(vb16, vl16, (RB)-48, dopf) BSTEP(vb17, vl17, (RB)-49, dopf)         \
        BSTEP(vb18, vl18, (RB)-50, dopf) BSTEP(vb19, vl19, (RB)-51, dopf)         \
        RENORM(a0, a1)                                                            \
        BSTEP(vb20, vl20, (RB)-52, dopf) BSTEP(vb21, vl21, (RB)-53, dopf)         \
        BSTEP(vb22, vl22, (RB)-54, dopf) BSTEP(vb23, vl23, (RB)-55, dopf)         \
        RENORM(a0, a1)                                                            \
        BSTEP(vb24, vl24, (RB)-56, dopf) BSTEP(vb25, vl25, (RB)-57, dopf)         \
        BSTEP(vb26, vl26, (RB)-58, dopf) BSTEP(vb27, vl27, (RB)-59, dopf)         \
        RENORM(a0, a1)                                                            \
        BSTEP(vb28, vl28, (RB)-60, dopf) BSTEP(vb29, vl29, (RB)-61, dopf)         \
        BSTEP(vb30, vl30, (RB)-62, dopf) BSTEP(vb31, vl31, (RB)-63, dopf)         \
        RENORM(a0, a1)

        // main: rows 511..288 (7 x 32), prefetch down to row 256 (valid)
        for (int r = 511; r >= 319; r -= 32) { BBLOCK(r, true) }
        // tail: rows 287..256 (32 steps, slots 0..31), no prefetch
        BBLOCK(0, false)
#undef BSTEP
#undef BBLOCK

        xb0[l] = a0; xb1[l] = a1; xEb[l] = E;
    }

    __syncthreads();

    if (w == 0) {
        // ======== combine: ll = sum_s alpha_255[s] * beta_255[s] ==========
        float B0 = xb0[l], B1 = xb1[l];
        int   EB = xEb[l];
        float c  = a0 * B0 + a1 * B1;     // scale 2^(E+EB)
        int   Ec = (c == 0.0f) ? (int)0xC0000000 : (E + EB);
        // in-row max of Ec (row_shr, keep-self = identity-safe)
        int m = Ec;
        m = max(m, dpp_i_keep<0x111>(m));
        m = max(m, dpp_i_keep<0x112>(m));
        m = max(m, dpp_i_keep<0x114>(m));
        m = max(m, dpp_i_keep<0x118>(m));
        if ((l & 15) == 15) rmax[l >> 4] = m;   // lane 15/31/47/63 = row max
        int Emax = max(max(rmax[0], rmax[1]), max(rmax[2], rmax[3]));
        // align + in-row sum (row_shr, 0-fill)
        float v = ldexpf(c, Ec - Emax);
        v += dpp_f0<0x111>(v);
        v += dpp_f0<0x112>(v);
        v += dpp_f0<0x114>(v);
        v += dpp_f0<0x118>(v);
        if ((l & 15) == 15) rsum[l >> 4] = v;
        if (l == 0) {
            float sum = rsum[0] + rsum[1] + rsum[2] + rsum[3];
            out[b] = -LN2f * (__log2f(sum) + (float)Emax);
        }
    }
}

extern "C" void kernel_launch(void* const* d_in, const int* in_sizes, int n_in,
                              void* d_out, int out_size, void* d_ws, size_t ws_size,
                              hipStream_t stream) {
    const int*   yt  = (const int*)d_in[0];
    const float* yp  = (const float*)d_in[1];
    float*       out = (float*)d_out;
    hipLaunchKernelGGL(ctc_fwd, dim3(Bn), dim3(128), 0, stream, yt, yp, out);
}